// Round 2
// baseline (423.860 us; speedup 1.0000x reference)
//
#include <hip/hip_runtime.h>

// Problem constants
#define BB   4
#define NN   30000
#define TT   12
#define EE   240000
#define FT   24        // F_IN * T contiguous floats per (b, node)

// Workspace layout (4-byte elements):
//   cnt     : [0, NN)                 int   incoming-edge count (excl self loop)
//   off     : [NN, NN+30016)          int   CSR offsets (NN+1 used, padded)
//   eff     : [60016, 60272)          float folded weights + softmax probs
//   csr_src : [60272, 300272)         int   edge sources grouped by dst
//   agg     : [300272, 3180272)       float aggregated features (B,N,FT)
#define WS_CNT 0
#define WS_OFF (NN)
#define WS_EFF (NN + 30016)
#define WS_CSR (NN + 30016 + 256)
#define WS_AGG (NN + 30016 + 256 + EE)

// ---- tiny weight-folding kernel: 1 block ----------------------------------
__global__ void k_prep(const float* __restrict__ czw, const float* __restrict__ czb,
                       const float* __restrict__ lzw, const float* __restrict__ lzb,
                       const float* __restrict__ chw, const float* __restrict__ chb,
                       const float* __restrict__ lhw, const float* __restrict__ lhb,
                       const float* __restrict__ att, float* __restrict__ eff) {
    int j = threadIdx.x;
    if (j < 32) {
        float wz0 = 0.f, wz1 = 0.f, bz = 0.f, wh0 = 0.f, wh1 = 0.f, bh = 0.f;
        for (int k = 0; k < 32; ++k) {
            float lz = lzw[k * 32 + j], lh = lhw[k * 32 + j];
            wz0 = fmaf(czw[k],      lz, wz0);
            wz1 = fmaf(czw[32 + k], lz, wz1);
            bz  = fmaf(czb[k],      lz, bz);
            wh0 = fmaf(chw[k],      lh, wh0);
            wh1 = fmaf(chw[32 + k], lh, wh1);
            bh  = fmaf(chb[k],      lh, bh);
        }
        eff[j]        = wz0;
        eff[32 + j]   = wz1;
        eff[64 + j]   = bz + lzb[j];
        eff[96 + j]   = wh0;
        eff[128 + j]  = wh1;
        eff[160 + j]  = bh + lhb[j];
    } else if (j == 32) {
        float m = -1e30f;
        for (int t = 0; t < TT; ++t) m = fmaxf(m, att[t]);
        float p[TT], s = 0.f;
        for (int t = 0; t < TT; ++t) { p[t] = __expf(att[t] - m); s += p[t]; }
        float inv = 1.0f / s;
        for (int t = 0; t < TT; ++t) eff[192 + t] = p[t] * inv;
    }
}

// ---- CSR build ------------------------------------------------------------
__global__ void k_zero(int* __restrict__ cnt) {
    int i = blockIdx.x * blockDim.x + threadIdx.x;
    if (i < NN) cnt[i] = 0;
}

__global__ void k_count(const int* __restrict__ dst, int* __restrict__ cnt) {
    int e = blockIdx.x * blockDim.x + threadIdx.x;
    if (e < EE) atomicAdd(&cnt[dst[e]], 1);
}

// single-block exclusive prefix scan of cnt[NN] -> off[NN] (+ off[NN]=total)
__global__ void __launch_bounds__(1024) k_scan(const int* __restrict__ cnt,
                                               int* __restrict__ off) {
    __shared__ int wsum[16];
    const int lt = threadIdx.x, lane = lt & 63, wid = lt >> 6;
    int carry = 0;
    for (int base = 0; base < NN; base += 1024) {
        int i = base + lt;
        int v = (i < NN) ? cnt[i] : 0;
        // inclusive wave scan
        int incl = v;
#pragma unroll
        for (int d = 1; d < 64; d <<= 1) {
            int t = __shfl_up(incl, d, 64);
            if (lane >= d) incl += t;
        }
        if (lane == 63) wsum[wid] = incl;
        __syncthreads();
        if (wid == 0) {
            int t = (lane < 16) ? wsum[lane] : 0;
#pragma unroll
            for (int d = 1; d < 16; d <<= 1) {
                int u = __shfl_up(t, d, 64);
                if (lane >= d) t += u;
            }
            if (lane < 16) wsum[lane] = t;  // inclusive wave-total scan
        }
        __syncthreads();
        int woff = (wid > 0) ? wsum[wid - 1] : 0;
        int excl = incl - v + woff + carry;
        if (i < NN) off[i] = excl;
        carry += wsum[15];
        __syncthreads();
    }
    if (lt == 0) off[NN] = carry;
}

// fill CSR; mutates off: afterwards off[n] == end-of-node-n (inclusive end)
__global__ void k_fill(const int* __restrict__ src, const int* __restrict__ dst,
                       int* __restrict__ off, int* __restrict__ csr_src) {
    int e = blockIdx.x * blockDim.x + threadIdx.x;
    if (e < EE) {
        int slot = atomicAdd(&off[dst[e]], 1);
        csr_src[slot] = src[e];
    }
}

// ---- gather: one wave per node, zero atomics ------------------------------
// post-fill offsets: start(n) = (n==0) ? 0 : off[n-1]; end(n) = off[n]
__global__ void __launch_bounds__(256) k_gather(const float* __restrict__ x,
                                                const int* __restrict__ cnt,
                                                const int* __restrict__ off,
                                                const int* __restrict__ csr_src,
                                                float* __restrict__ agg) {
    int wave = (blockIdx.x * 256 + threadIdx.x) >> 6;   // == node id
    int lane = threadIdx.x & 63;
    if (wave >= NN) return;
    const int n = wave;

    // lane -> two of the 96 (b,ft) cells: cell0 = lane, cell1 = 64+lane (lane<32)
    int c0 = lane, c1 = 64 + lane;
    int b0 = c0 / FT, f0 = c0 - FT * b0;
    int b1 = c1 / FT, f1 = c1 - FT * b1;
    long long base0 = (long long)b0 * NN * FT + f0;
    long long base1 = (long long)b1 * NN * FT + f1;

    int start = (n == 0) ? 0 : off[n - 1];
    int end = off[n];

    float dn = rsqrtf((float)(cnt[n] + 1));   // self-loop deg includes +1
    float self_w = dn * dn;
    float acc0 = x[base0 + (long long)n * FT] * self_w;
    float acc1 = (lane < 32) ? x[base1 + (long long)n * FT] * self_w : 0.f;

    for (int k = start; k < end; ++k) {
        int s = csr_src[k];                       // broadcast load
        float ds = rsqrtf((float)(cnt[s] + 1));   // broadcast load
        float w = ds * dn;
        acc0 = fmaf(w, x[base0 + (long long)s * FT], acc0);
        if (lane < 32) acc1 = fmaf(w, x[base1 + (long long)s * FT], acc1);
    }

    agg[base0 + (long long)n * FT] = acc0;
    if (lane < 32) agg[base1 + (long long)n * FT] = acc1;
}

// ---- per-node combine: gates + attention sum + head -----------------------
__global__ void __launch_bounds__(256)
k_node(const float* __restrict__ agg, const float* __restrict__ eff,
       const float* __restrict__ hw, const float* __restrict__ hb,
       float* __restrict__ out) {
    __shared__ float s[608];   // eff[204] | head_w[384] | head_b[12]
    int lt = threadIdx.x;
    for (int i = lt; i < 204; i += 256) s[i] = eff[i];
    for (int i = lt; i < 384; i += 256) s[204 + i] = hw[i];
    if (lt < 12) s[588 + lt] = hb[lt];
    __syncthreads();

    int tid = blockIdx.x * 256 + lt;   // over BB*NN
    if (tid >= BB * NN) return;

    float4 buf[6];
    const float4* a4 = reinterpret_cast<const float4*>(agg + (long long)tid * FT);
#pragma unroll
    for (int i = 0; i < 6; ++i) buf[i] = a4[i];
    const float* av = reinterpret_cast<const float*>(buf);  // av[f*12 + t]

    float acc[32];
#pragma unroll
    for (int j = 0; j < 32; ++j) acc[j] = 0.f;

#pragma unroll
    for (int t = 0; t < TT; ++t) {
        float v0 = av[t], v1 = av[12 + t], p = s[192 + t];
#pragma unroll
        for (int j = 0; j < 32; ++j) {
            float zp = fmaf(v1, s[32 + j],  fmaf(v0, s[j],      s[64 + j]));
            float hp = fmaf(v1, s[128 + j], fmaf(v0, s[96 + j], s[160 + j]));
            float z  = 1.0f / (1.0f + __expf(-zp));
            hp = fminf(fmaxf(hp, -15.0f), 15.0f);
            float e2 = __expf(2.0f * hp);
            float h  = (e2 - 1.0f) / (e2 + 1.0f);
            acc[j] = fmaf(p * (1.0f - z), h, acc[j]);
        }
    }

#pragma unroll
    for (int j = 0; j < 32; ++j) acc[j] = fmaxf(acc[j], 0.f);

    float* o = out + (long long)tid * 12;
#pragma unroll
    for (int k = 0; k < 12; ++k) {
        float r = s[588 + k];
#pragma unroll
        for (int j = 0; j < 32; ++j) r = fmaf(acc[j], s[204 + j * 12 + k], r);
        o[k] = r;
    }
}

extern "C" void kernel_launch(void* const* d_in, const int* in_sizes, int n_in,
                              void* d_out, int out_size, void* d_ws, size_t ws_size,
                              hipStream_t stream) {
    const float* x   = (const float*)d_in[0];
    const int*   ei  = (const int*)d_in[1];     // (2,E): [0,E)=src, [E,2E)=dst
    const float* att = (const float*)d_in[2];
    const float* czw = (const float*)d_in[3];
    const float* czb = (const float*)d_in[4];
    const float* lzw = (const float*)d_in[5];
    const float* lzb = (const float*)d_in[6];
    // d_in[7..10] (conv_r / lin_r) are dead: H0 == 0 so H0*R == 0
    const float* chw = (const float*)d_in[11];
    const float* chb = (const float*)d_in[12];
    const float* lhw = (const float*)d_in[13];
    const float* lhb = (const float*)d_in[14];
    const float* hw  = (const float*)d_in[15];
    const float* hb  = (const float*)d_in[16];
    float* out = (float*)d_out;

    float* ws = (float*)d_ws;
    int*   cnt = (int*)(ws + WS_CNT);
    int*   off = (int*)(ws + WS_OFF);
    float* eff = ws + WS_EFF;
    int*   csr = (int*)(ws + WS_CSR);
    float* agg = ws + WS_AGG;

    const int* src = ei;
    const int* dst = ei + EE;

    k_prep<<<1, 64, 0, stream>>>(czw, czb, lzw, lzb, chw, chb, lhw, lhb, att, eff);
    k_zero<<<(NN + 255) / 256, 256, 0, stream>>>(cnt);
    k_count<<<(EE + 255) / 256, 256, 0, stream>>>(dst, cnt);
    k_scan<<<1, 1024, 0, stream>>>(cnt, off);
    k_fill<<<(EE + 255) / 256, 256, 0, stream>>>(src, dst, off, csr);
    k_gather<<<(NN * 64 + 255) / 256, 256, 0, stream>>>(x, cnt, off, csr, agg);
    k_node<<<(BB * NN + 255) / 256, 256, 0, stream>>>(agg, eff, hw, hb, out);
}

// Round 3
// 202.772 us; speedup vs baseline: 2.0903x; 2.0903x over previous
//
#include <hip/hip_runtime.h>

// Problem constants
#define BB   4
#define NN   30000
#define TT   12
#define EE   240000
#define FT   24        // F_IN * T contiguous floats per (b, node)
#define ROWS (BB * NN) // 120000 rows of 24 aggregated features
#define SCAN_BLOCKS ((NN + 255) / 256)   // 118

// Workspace layout (4-byte elements):
#define WS_CNT 0                          // int cnt[NN]
#define WS_OFF (NN)                       // int off[NN+pad]
#define WS_BT  (NN + 30016)               // int btot[128]
#define WS_EFF (NN + 30016 + 128)         // float eff[256]
#define WS_CSR (NN + 30016 + 128 + 256)   // int csr_src[EE]
#define WS_AGG (NN + 30016 + 128 + 256 + EE) // float agg[ROWS*FT]

// ---- tiny weight-folding kernel: 1 block ----------------------------------
// eff: Wz0[32] Wz1[32] bz[32] Wh0[32] Wh1[32] bh[32] probs[12]
__global__ void k_prep(const float* __restrict__ czw, const float* __restrict__ czb,
                       const float* __restrict__ lzw, const float* __restrict__ lzb,
                       const float* __restrict__ chw, const float* __restrict__ chb,
                       const float* __restrict__ lhw, const float* __restrict__ lhb,
                       const float* __restrict__ att, float* __restrict__ eff) {
    int j = threadIdx.x;
    if (j < 32) {
        float wz0 = 0.f, wz1 = 0.f, bz = 0.f, wh0 = 0.f, wh1 = 0.f, bh = 0.f;
        for (int k = 0; k < 32; ++k) {
            float lz = lzw[k * 32 + j], lh = lhw[k * 32 + j];
            wz0 = fmaf(czw[k],      lz, wz0);
            wz1 = fmaf(czw[32 + k], lz, wz1);
            bz  = fmaf(czb[k],      lz, bz);
            wh0 = fmaf(chw[k],      lh, wh0);
            wh1 = fmaf(chw[32 + k], lh, wh1);
            bh  = fmaf(chb[k],      lh, bh);
        }
        eff[j]        = wz0;
        eff[32 + j]   = wz1;
        eff[64 + j]   = bz + lzb[j];
        eff[96 + j]   = wh0;
        eff[128 + j]  = wh1;
        eff[160 + j]  = bh + lhb[j];
    } else if (j == 32) {
        float m = -1e30f;
        for (int t = 0; t < TT; ++t) m = fmaxf(m, att[t]);
        float p[TT], s = 0.f;
        for (int t = 0; t < TT; ++t) { p[t] = __expf(att[t] - m); s += p[t]; }
        float inv = 1.0f / s;
        for (int t = 0; t < TT; ++t) eff[192 + t] = p[t] * inv;
    }
}

// ---- CSR build ------------------------------------------------------------
__global__ void k_zero(int* __restrict__ cnt) {
    int i = blockIdx.x * blockDim.x + threadIdx.x;
    if (i < NN) cnt[i] = 0;
}

__global__ void k_count(const int* __restrict__ dst, int* __restrict__ cnt) {
    int e = blockIdx.x * blockDim.x + threadIdx.x;
    if (e < EE) atomicAdd(&cnt[dst[e]], 1);
}

// local exclusive scan per 256-block; write per-block totals
__global__ void __launch_bounds__(256) k_scan_local(const int* __restrict__ cnt,
                                                    int* __restrict__ off,
                                                    int* __restrict__ btot) {
    __shared__ int wtot[4];
    int lt = threadIdx.x, lane = lt & 63, wid = lt >> 6;
    int i = blockIdx.x * 256 + lt;
    int v = (i < NN) ? cnt[i] : 0;
    int incl = v;
#pragma unroll
    for (int d = 1; d < 64; d <<= 1) {
        int t = __shfl_up(incl, d, 64);
        if (lane >= d) incl += t;
    }
    if (lane == 63) wtot[wid] = incl;
    __syncthreads();
    int wbase = 0;
#pragma unroll
    for (int w = 0; w < 4; ++w) if (w < wid) wbase += wtot[w];
    if (i < NN) off[i] = incl - v + wbase;
    if (lt == 255) btot[blockIdx.x] = wbase + incl;   // block total
}

// single-block exclusive scan of the 118 block totals (in place)
__global__ void __launch_bounds__(128) k_scan_base(int* __restrict__ btot) {
    __shared__ int wtot[2];
    int lt = threadIdx.x, lane = lt & 63, wid = lt >> 6;
    int v = (lt < SCAN_BLOCKS) ? btot[lt] : 0;
    int incl = v;
#pragma unroll
    for (int d = 1; d < 64; d <<= 1) {
        int t = __shfl_up(incl, d, 64);
        if (lane >= d) incl += t;
    }
    if (lane == 63) wtot[wid] = incl;
    __syncthreads();
    int wbase = (wid == 1) ? wtot[0] : 0;
    if (lt < SCAN_BLOCKS) btot[lt] = incl - v + wbase;
    __syncthreads();
}

__global__ void k_scan_add(int* __restrict__ off, const int* __restrict__ btot) {
    int i = blockIdx.x * blockDim.x + threadIdx.x;
    if (i < NN) off[i] += btot[blockIdx.x];
}

// fill CSR; mutates off: afterwards off[n] == end-of-node-n
__global__ void k_fill(const int* __restrict__ src, const int* __restrict__ dst,
                       int* __restrict__ off, int* __restrict__ csr_src) {
    int e = blockIdx.x * blockDim.x + threadIdx.x;
    if (e < EE) {
        int slot = atomicAdd(&off[dst[e]], 1);
        csr_src[slot] = src[e];
    }
}

// ---- gather: one wave per node, zero atomics ------------------------------
// post-fill offsets: start(n) = (n==0) ? 0 : off[n-1]; end(n) = off[n]
__global__ void __launch_bounds__(256) k_gather(const float* __restrict__ x,
                                                const int* __restrict__ cnt,
                                                const int* __restrict__ off,
                                                const int* __restrict__ csr_src,
                                                float* __restrict__ agg) {
    int wave = (blockIdx.x * 256 + threadIdx.x) >> 6;   // == node id
    int lane = threadIdx.x & 63;
    if (wave >= NN) return;
    const int n = wave;

    int c0 = lane, c1 = 64 + lane;
    int b0 = c0 / FT, f0 = c0 - FT * b0;
    int b1 = c1 / FT, f1 = c1 - FT * b1;
    long long base0 = (long long)b0 * NN * FT + f0;
    long long base1 = (long long)b1 * NN * FT + f1;

    int start = (n == 0) ? 0 : off[n - 1];
    int end = off[n];

    float dn = rsqrtf((float)(cnt[n] + 1));
    float self_w = dn * dn;
    float acc0 = x[base0 + (long long)n * FT] * self_w;
    float acc1 = (lane < 32) ? x[base1 + (long long)n * FT] * self_w : 0.f;

    for (int k = start; k < end; ++k) {
        int s = csr_src[k];
        float ds = rsqrtf((float)(cnt[s] + 1));
        float w = ds * dn;
        acc0 = fmaf(w, x[base0 + (long long)s * FT], acc0);
        if (lane < 32) acc1 = fmaf(w, x[base1 + (long long)s * FT], acc1);
    }

    agg[base0 + (long long)n * FT] = acc0;
    if (lane < 32) agg[base1 + (long long)n * FT] = acc1;
}

// ---- per-(row,j) combine: 32 threads per row, 8 rows per block ------------
__global__ void __launch_bounds__(256)
k_node(const float* __restrict__ agg, const float* __restrict__ eff,
       const float* __restrict__ hw, const float* __restrict__ hb,
       float* __restrict__ out) {
    __shared__ float sa[192];    // 8 rows x 24 feats
    __shared__ float se[204];    // folded weights + probs
    __shared__ float shw[384];   // head_w
    __shared__ float shb[12];    // head_b
    __shared__ float lacc[256];  // 8 rows x 32 relu'd hidden
    const int lt = threadIdx.x;
    const int nl = lt >> 5;      // row within block (0..7)
    const int j  = lt & 31;      // hidden unit

    if (lt < 192) sa[lt] = agg[blockIdx.x * 192 + lt];
    if (lt < 204) se[lt] = eff[lt];
    shw[lt] = hw[lt & 255 | ((lt >> 8) << 8)];            // lt < 256
    if (lt < 128) shw[256 + lt] = hw[256 + lt];
    if (lt < 12) shb[lt] = hb[lt];
    __syncthreads();

    const float wz0 = se[j],       wz1 = se[32 + j],  bz = se[64 + j];
    const float wh0 = se[96 + j],  wh1 = se[128 + j], bh = se[160 + j];
    const float* srow = sa + nl * 24;

    float acc = 0.f;
#pragma unroll
    for (int t = 0; t < TT; ++t) {
        float v0 = srow[t], v1 = srow[12 + t], p = se[192 + t];
        float zp = fmaf(v1, wz1, fmaf(v0, wz0, bz));
        float inv = __builtin_amdgcn_rcpf(1.0f + __expf(zp));   // 1 - sigmoid(zp)
        float hp = fmaf(v1, wh1, fmaf(v0, wh0, bh));
        hp = fminf(fmaxf(hp + hp, -30.0f), 30.0f);
        float e2 = __expf(hp);
        float h  = (e2 - 1.0f) * __builtin_amdgcn_rcpf(e2 + 1.0f);  // tanh
        acc = fmaf(p * inv, h, acc);
    }

    lacc[lt] = fmaxf(acc, 0.f);   // relu'd hidden, lacc[nl*32 + j]
    __syncthreads();

    if (lt < 96) {                 // 8 rows x 12 outputs
        int q = lt / 12, k = lt - 12 * q;
        float r = shb[k];
#pragma unroll
        for (int jj = 0; jj < 32; ++jj)
            r = fmaf(lacc[q * 32 + jj], shw[jj * 12 + k], r);
        out[blockIdx.x * 96 + lt] = r;
    }
}

extern "C" void kernel_launch(void* const* d_in, const int* in_sizes, int n_in,
                              void* d_out, int out_size, void* d_ws, size_t ws_size,
                              hipStream_t stream) {
    const float* x   = (const float*)d_in[0];
    const int*   ei  = (const int*)d_in[1];     // (2,E): [0,E)=src, [E,2E)=dst
    const float* att = (const float*)d_in[2];
    const float* czw = (const float*)d_in[3];
    const float* czb = (const float*)d_in[4];
    const float* lzw = (const float*)d_in[5];
    const float* lzb = (const float*)d_in[6];
    // d_in[7..10] (conv_r / lin_r) dead: H0 == 0 so H0*R == 0
    const float* chw = (const float*)d_in[11];
    const float* chb = (const float*)d_in[12];
    const float* lhw = (const float*)d_in[13];
    const float* lhb = (const float*)d_in[14];
    const float* hw  = (const float*)d_in[15];
    const float* hb  = (const float*)d_in[16];
    float* out = (float*)d_out;

    float* ws = (float*)d_ws;
    int*   cnt  = (int*)(ws + WS_CNT);
    int*   off  = (int*)(ws + WS_OFF);
    int*   btot = (int*)(ws + WS_BT);
    float* eff  = ws + WS_EFF;
    int*   csr  = (int*)(ws + WS_CSR);
    float* agg  = ws + WS_AGG;

    const int* src = ei;
    const int* dst = ei + EE;

    k_prep<<<1, 64, 0, stream>>>(czw, czb, lzw, lzb, chw, chb, lhw, lhb, att, eff);
    k_zero<<<(NN + 255) / 256, 256, 0, stream>>>(cnt);
    k_count<<<(EE + 255) / 256, 256, 0, stream>>>(dst, cnt);
    k_scan_local<<<SCAN_BLOCKS, 256, 0, stream>>>(cnt, off, btot);
    k_scan_base<<<1, 128, 0, stream>>>(btot);
    k_scan_add<<<SCAN_BLOCKS, 256, 0, stream>>>(off, btot);
    k_fill<<<(EE + 255) / 256, 256, 0, stream>>>(src, dst, off, csr);
    k_gather<<<(NN * 64 + 255) / 256, 256, 0, stream>>>(x, cnt, off, csr, agg);
    k_node<<<ROWS / 8, 256, 0, stream>>>(agg, eff, hw, hb, out);
}

// Round 4
// 188.710 us; speedup vs baseline: 2.2461x; 1.0745x over previous
//
#include <hip/hip_runtime.h>

// Problem constants
#define BB   4
#define NN   30000
#define TT   12
#define EE   240000
#define FT   24        // F_IN * T floats per (b, node)
#define NM   96        // BB * FT: node-major row length
#define SCAN_BLOCKS ((NN + 255) / 256)   // 118
#define TRB  (NN * NM / 256)             // 11250 transpose blocks

// Workspace layout (4-byte elements) — identical footprint to R3 (3,180,400):
#define WS_CNT 0                          // int   cnt[NN]
#define WS_OFF (NN)                       // int   off[30016]
#define WS_BT  (NN + 30016)               // int   btot[128]
#define WS_EFF (NN + 30016 + 128)         // float eff[256]
#define WS_CSR (NN + 30016 + 128 + 256)   // int   csr_src[EE]
#define WS_XT  (NN + 30016 + 128 + 256 + EE) // float xt[NN*96] node-major

// ---- fused: transpose x -> xt, zero cnt, fold weights ---------------------
// eff: Wz0[32] Wz1[32] bz[32] Wh0[32] Wh1[32] bh[32] probs[12]
__global__ void __launch_bounds__(256)
k_pre(const float* __restrict__ x,
      const float* __restrict__ czw, const float* __restrict__ czb,
      const float* __restrict__ lzw, const float* __restrict__ lzb,
      const float* __restrict__ chw, const float* __restrict__ chb,
      const float* __restrict__ lhw, const float* __restrict__ lhb,
      const float* __restrict__ att,
      float* __restrict__ xt, int* __restrict__ cnt, float* __restrict__ eff) {
    int bid = blockIdx.x, lt = threadIdx.x;
    if (bid < TRB) {
        // transpose: xt[n*96 + b*24 + ft] = x[(b*NN + n)*24 + ft]
        int tid = bid * 256 + lt;
        int n = tid / NM, c = tid - NM * n;
        int b = c / FT, ft = c - FT * b;
        xt[tid] = x[(b * NN + n) * FT + ft];
        // first blocks also zero cnt (same kernel, finishes before k_count)
        int zi = bid * 256 + lt;
        if (zi < NN) cnt[zi] = 0;
        return;
    }
    // last block: weight folding + attention softmax
    int j = lt;
    if (j < 32) {
        float wz0 = 0.f, wz1 = 0.f, bz = 0.f, wh0 = 0.f, wh1 = 0.f, bh = 0.f;
        for (int k = 0; k < 32; ++k) {
            float lz = lzw[k * 32 + j], lh = lhw[k * 32 + j];
            wz0 = fmaf(czw[k],      lz, wz0);
            wz1 = fmaf(czw[32 + k], lz, wz1);
            bz  = fmaf(czb[k],      lz, bz);
            wh0 = fmaf(chw[k],      lh, wh0);
            wh1 = fmaf(chw[32 + k], lh, wh1);
            bh  = fmaf(chb[k],      lh, bh);
        }
        eff[j]        = wz0;
        eff[32 + j]   = wz1;
        eff[64 + j]   = bz + lzb[j];
        eff[96 + j]   = wh0;
        eff[128 + j]  = wh1;
        eff[160 + j]  = bh + lhb[j];
    } else if (j == 32) {
        float m = -1e30f;
        for (int t = 0; t < TT; ++t) m = fmaxf(m, att[t]);
        float p[TT], s = 0.f;
        for (int t = 0; t < TT; ++t) { p[t] = __expf(att[t] - m); s += p[t]; }
        float inv = 1.0f / s;
        for (int t = 0; t < TT; ++t) eff[192 + t] = p[t] * inv;
    }
}

// ---- CSR build ------------------------------------------------------------
__global__ void k_count(const int* __restrict__ dst, int* __restrict__ cnt) {
    int e = blockIdx.x * blockDim.x + threadIdx.x;
    if (e < EE) atomicAdd(&cnt[dst[e]], 1);
}

// local exclusive scan per 256-block; write per-block totals
__global__ void __launch_bounds__(256) k_scan_local(const int* __restrict__ cnt,
                                                    int* __restrict__ off,
                                                    int* __restrict__ btot) {
    __shared__ int wtot[4];
    int lt = threadIdx.x, lane = lt & 63, wid = lt >> 6;
    int i = blockIdx.x * 256 + lt;
    int v = (i < NN) ? cnt[i] : 0;
    int incl = v;
#pragma unroll
    for (int d = 1; d < 64; d <<= 1) {
        int t = __shfl_up(incl, d, 64);
        if (lane >= d) incl += t;
    }
    if (lane == 63) wtot[wid] = incl;
    __syncthreads();
    int wbase = 0;
#pragma unroll
    for (int w = 0; w < 4; ++w) if (w < wid) wbase += wtot[w];
    if (i < NN) off[i] = incl - v + wbase;
    if (lt == 255) btot[blockIdx.x] = wbase + incl;
}

// add global base: each block reduces btot[0..bid-1] itself (118 entries max)
__global__ void __launch_bounds__(256) k_scan_add(int* __restrict__ off,
                                                  const int* __restrict__ btot) {
    __shared__ int sbase;
    int lt = threadIdx.x, bid = blockIdx.x;
    if (lt < 64) {
        int s = 0;
        for (int i = lt; i < bid; i += 64) s += btot[i];
#pragma unroll
        for (int d = 32; d > 0; d >>= 1) s += __shfl_down(s, d, 64);
        if (lt == 0) sbase = s;
    }
    __syncthreads();
    int i = bid * 256 + lt;
    if (i < NN) off[i] += sbase;
}

// fill CSR; mutates off: afterwards off[n] == end-of-node-n
__global__ void k_fill(const int* __restrict__ src, const int* __restrict__ dst,
                       int* __restrict__ off, int* __restrict__ csr_src) {
    int e = blockIdx.x * blockDim.x + threadIdx.x;
    if (e < EE) {
        int slot = atomicAdd(&off[dst[e]], 1);
        csr_src[slot] = src[e];
    }
}

// ---- fused gather + gates + head: one wave per node -----------------------
__global__ void __launch_bounds__(256)
k_fused(const float* __restrict__ xt, const int* __restrict__ cnt,
        const int* __restrict__ off, const int* __restrict__ csr_src,
        const float* __restrict__ eff, const float* __restrict__ hw,
        const float* __restrict__ hb, float* __restrict__ out) {
    __shared__ float se[204];          // folded weights + probs
    __shared__ float shw[384];         // head_w (32x12)
    __shared__ float shb[12];          // head_b
    __shared__ float sx[4 * NM];       // per-wave aggregated row
    __shared__ float lacc[4 * 132];    // per-wave relu'd hidden (stride 33)
    const int lt = threadIdx.x, lane = lt & 63, w = lt >> 6;
    const int n = blockIdx.x * 4 + w;  // 7500 blocks * 4 waves = 30000 nodes

    if (lt < 204) se[lt] = eff[lt];
    if (lt >= 204 && lt < 216) shb[lt - 204] = hb[lt - 204];
    {
        int i = lt;
        shw[i] = hw[i];
        if (i < 128) shw[256 + i] = hw[256 + i];
    }
    __syncthreads();

    // ---- gather (node-major rows: lane-coalesced, zero atomics) ----
    const int start = (n == 0) ? 0 : off[n - 1];
    const int end = off[n];
    const float dn = rsqrtf((float)(cnt[n] + 1));
    const float* rown = xt + (long long)n * NM;
    float acc0 = rown[lane] * (dn * dn);
    float acc1 = (lane < 32) ? rown[64 + lane] * (dn * dn) : 0.f;
    for (int k = start; k < end; ++k) {
        int s = csr_src[k];                         // wave-uniform
        float ws_ = dn * rsqrtf((float)(cnt[s] + 1));
        const float* rows = xt + (long long)s * NM;
        acc0 = fmaf(ws_, rows[lane], acc0);
        if (lane < 32) acc1 = fmaf(ws_, rows[64 + lane], acc1);
    }
    sx[w * NM + lane] = acc0;
    if (lane < 32) sx[w * NM + 64 + lane] = acc1;
    __syncthreads();

    // ---- gates: lane handles (b0, j) and (b0+2, j) ----
    const int j = lane & 31, b0 = lane >> 5;
    const float wz0 = se[j],      wz1 = se[32 + j],  bz = se[64 + j];
    const float wh0 = se[96 + j], wh1 = se[128 + j], bh = se[160 + j];
#pragma unroll
    for (int bi = 0; bi < 2; ++bi) {
        const int b = b0 + 2 * bi;
        const float* srow = sx + w * NM + b * FT;
        float a = 0.f;
#pragma unroll
        for (int t = 0; t < TT; ++t) {
            float v0 = srow[t], v1 = srow[12 + t], p = se[192 + t];
            float zp = fmaf(v1, wz1, fmaf(v0, wz0, bz));
            float inv = __builtin_amdgcn_rcpf(1.0f + __expf(zp));   // 1 - sigmoid
            float hp = fmaf(v1, wh1, fmaf(v0, wh0, bh));
            hp = fminf(fmaxf(hp + hp, -30.0f), 30.0f);
            float e2 = __expf(hp);
            float h  = (e2 - 1.0f) * __builtin_amdgcn_rcpf(e2 + 1.0f);  // tanh
            a = fmaf(p * inv, h, a);
        }
        lacc[w * 132 + b * 33 + j] = fmaxf(a, 0.f);
    }
    __syncthreads();

    // ---- head: lanes 0..47 produce (b, k) ----
    if (lane < 48) {
        int b = lane / 12, k = lane - 12 * b;
        float r = shb[k];
        const float* la = lacc + w * 132 + b * 33;
#pragma unroll
        for (int jj = 0; jj < 32; ++jj)
            r = fmaf(la[jj], shw[jj * 12 + k], r);
        out[((long long)b * NN + n) * 12 + k] = r;
    }
}

extern "C" void kernel_launch(void* const* d_in, const int* in_sizes, int n_in,
                              void* d_out, int out_size, void* d_ws, size_t ws_size,
                              hipStream_t stream) {
    const float* x   = (const float*)d_in[0];
    const int*   ei  = (const int*)d_in[1];     // (2,E): [0,E)=src, [E,2E)=dst
    const float* att = (const float*)d_in[2];
    const float* czw = (const float*)d_in[3];
    const float* czb = (const float*)d_in[4];
    const float* lzw = (const float*)d_in[5];
    const float* lzb = (const float*)d_in[6];
    // d_in[7..10] (conv_r / lin_r) dead: H0 == 0 so H0*R == 0
    const float* chw = (const float*)d_in[11];
    const float* chb = (const float*)d_in[12];
    const float* lhw = (const float*)d_in[13];
    const float* lhb = (const float*)d_in[14];
    const float* hw  = (const float*)d_in[15];
    const float* hb  = (const float*)d_in[16];
    float* out = (float*)d_out;

    float* ws = (float*)d_ws;
    int*   cnt  = (int*)(ws + WS_CNT);
    int*   off  = (int*)(ws + WS_OFF);
    int*   btot = (int*)(ws + WS_BT);
    float* eff  = ws + WS_EFF;
    int*   csr  = (int*)(ws + WS_CSR);
    float* xt   = ws + WS_XT;

    const int* src = ei;
    const int* dst = ei + EE;

    k_pre<<<TRB + 1, 256, 0, stream>>>(x, czw, czb, lzw, lzb, chw, chb,
                                       lhw, lhb, att, xt, cnt, eff);
    k_count<<<(EE + 255) / 256, 256, 0, stream>>>(dst, cnt);
    k_scan_local<<<SCAN_BLOCKS, 256, 0, stream>>>(cnt, off, btot);
    k_scan_add<<<SCAN_BLOCKS, 256, 0, stream>>>(off, btot);
    k_fill<<<(EE + 255) / 256, 256, 0, stream>>>(src, dst, off, csr);
    k_fused<<<NN / 4, 256, 0, stream>>>(xt, cnt, off, csr, eff, hw, hb, out);
}

// Round 5
// 173.909 us; speedup vs baseline: 2.4373x; 1.0851x over previous
//
#include <hip/hip_runtime.h>

// Problem constants
#define BB   4
#define NN   30000
#define TT   12
#define EE   240000
#define FT   24        // F_IN * T floats per (b, node)
#define NM   96        // BB * FT: node-major row length
#define SCAN_BLOCKS ((NN + 255) / 256)   // 118
#define TRB  (NN * NM / 256)             // 11250 transpose blocks

// Workspace layout (4-byte elements) — identical footprint to R4 (3,180,400):
#define WS_CNT 0                          // int   cnt[NN]
#define WS_OFF (NN)                       // int   off[30016]
#define WS_BT  (NN + 30016)               // int   btot[128]
#define WS_EFF (NN + 30016 + 128)         // float eff[256]
#define WS_CSR (NN + 30016 + 128 + 256)   // int   csr_src[EE]
#define WS_XT  (NN + 30016 + 128 + 256 + EE) // float xt[NN*96] node-major

// ---- fused: transpose x -> xt, zero cnt, fold weights ---------------------
// eff: Wz0[32] Wz1[32] bz[32] Wh0[32] Wh1[32] bh[32] probs[12]
__global__ void __launch_bounds__(256)
k_pre(const float* __restrict__ x,
      const float* __restrict__ czw, const float* __restrict__ czb,
      const float* __restrict__ lzw, const float* __restrict__ lzb,
      const float* __restrict__ chw, const float* __restrict__ chb,
      const float* __restrict__ lhw, const float* __restrict__ lhb,
      const float* __restrict__ att,
      float* __restrict__ xt, int* __restrict__ cnt, float* __restrict__ eff) {
    int bid = blockIdx.x, lt = threadIdx.x;
    if (bid < TRB) {
        // transpose: xt[n*96 + b*24 + ft] = x[(b*NN + n)*24 + ft]
        int tid = bid * 256 + lt;
        int n = tid / NM, c = tid - NM * n;
        int b = c / FT, ft = c - FT * b;
        xt[tid] = x[(b * NN + n) * FT + ft];
        int zi = bid * 256 + lt;
        if (zi < NN) cnt[zi] = 0;
        return;
    }
    // last block: weight folding + attention softmax
    int j = lt;
    if (j < 32) {
        float wz0 = 0.f, wz1 = 0.f, bz = 0.f, wh0 = 0.f, wh1 = 0.f, bh = 0.f;
        for (int k = 0; k < 32; ++k) {
            float lz = lzw[k * 32 + j], lh = lhw[k * 32 + j];
            wz0 = fmaf(czw[k],      lz, wz0);
            wz1 = fmaf(czw[32 + k], lz, wz1);
            bz  = fmaf(czb[k],      lz, bz);
            wh0 = fmaf(chw[k],      lh, wh0);
            wh1 = fmaf(chw[32 + k], lh, wh1);
            bh  = fmaf(chb[k],      lh, bh);
        }
        eff[j]        = wz0;
        eff[32 + j]   = wz1;
        eff[64 + j]   = bz + lzb[j];
        eff[96 + j]   = wh0;
        eff[128 + j]  = wh1;
        eff[160 + j]  = bh + lhb[j];
    } else if (j == 32) {
        float m = -1e30f;
        for (int t = 0; t < TT; ++t) m = fmaxf(m, att[t]);
        float p[TT], s = 0.f;
        for (int t = 0; t < TT; ++t) { p[t] = __expf(att[t] - m); s += p[t]; }
        float inv = 1.0f / s;
        for (int t = 0; t < TT; ++t) eff[192 + t] = p[t] * inv;
    }
}

// ---- CSR build ------------------------------------------------------------
__global__ void k_count(const int* __restrict__ dst, int* __restrict__ cnt) {
    int e = blockIdx.x * blockDim.x + threadIdx.x;
    if (e < EE) atomicAdd(&cnt[dst[e]], 1);
}

// local exclusive scan per 256-block; write per-block totals
__global__ void __launch_bounds__(256) k_scan_local(const int* __restrict__ cnt,
                                                    int* __restrict__ off,
                                                    int* __restrict__ btot) {
    __shared__ int wtot[4];
    int lt = threadIdx.x, lane = lt & 63, wid = lt >> 6;
    int i = blockIdx.x * 256 + lt;
    int v = (i < NN) ? cnt[i] : 0;
    int incl = v;
#pragma unroll
    for (int d = 1; d < 64; d <<= 1) {
        int t = __shfl_up(incl, d, 64);
        if (lane >= d) incl += t;
    }
    if (lane == 63) wtot[wid] = incl;
    __syncthreads();
    int wbase = 0;
#pragma unroll
    for (int w = 0; w < 4; ++w) if (w < wid) wbase += wtot[w];
    if (i < NN) off[i] = incl - v + wbase;
    if (lt == 255) btot[blockIdx.x] = wbase + incl;
}

// add global base: each block reduces btot[0..bid-1] itself
__global__ void __launch_bounds__(256) k_scan_add(int* __restrict__ off,
                                                  const int* __restrict__ btot) {
    __shared__ int sbase;
    int lt = threadIdx.x, bid = blockIdx.x;
    if (lt < 64) {
        int s = 0;
        for (int i = lt; i < bid; i += 64) s += btot[i];
#pragma unroll
        for (int d = 32; d > 0; d >>= 1) s += __shfl_down(s, d, 64);
        if (lt == 0) sbase = s;
    }
    __syncthreads();
    int i = bid * 256 + lt;
    if (i < NN) off[i] += sbase;
}

// fill CSR; mutates off: afterwards off[n] == end-of-node-n
__global__ void k_fill(const int* __restrict__ src, const int* __restrict__ dst,
                       int* __restrict__ off, int* __restrict__ csr_src) {
    int e = blockIdx.x * blockDim.x + threadIdx.x;
    if (e < EE) {
        int slot = atomicAdd(&off[dst[e]], 1);
        csr_src[slot] = src[e];
    }
}

// ---- fused gather + gates + head: one wave per node -----------------------
__global__ void __launch_bounds__(256)
k_fused(const float* __restrict__ xt, const int* __restrict__ cnt,
        const int* __restrict__ off, const int* __restrict__ csr_src,
        const float* __restrict__ eff, const float* __restrict__ hw,
        const float* __restrict__ hb, float* __restrict__ out) {
    __shared__ float se[204];          // folded weights + probs
    __shared__ float shw[384];         // head_w (32x12)
    __shared__ float shb[12];          // head_b
    __shared__ float sx[4 * NM];       // per-wave aggregated row
    __shared__ float lacc[4 * 132];    // per-wave relu'd hidden (stride 33)
    const int lt = threadIdx.x, lane = lt & 63, w = lt >> 6;
    const int n = blockIdx.x * 4 + w;  // 7500 blocks * 4 waves = 30000 nodes

    if (lt < 204) se[lt] = eff[lt];
    if (lt >= 204 && lt < 216) shb[lt - 204] = hb[lt - 204];
    {
        int i = lt;
        shw[i] = hw[i];
        if (i < 128) shw[256 + i] = hw[256 + i];
    }
    __syncthreads();

    // ---- gather: chunk-of-4 manual MLP (all loads issued before use) ----
    const int start = (n == 0) ? 0 : off[n - 1];
    const int end = off[n];
    const float dn = rsqrtf((float)(cnt[n] + 1));
    const float* rown = xt + (long long)n * NM;
    float acc0 = rown[lane] * (dn * dn);
    float acc1 = (lane < 32) ? rown[64 + lane] * (dn * dn) : 0.f;

    int k = start;
    for (; k + 4 <= end; k += 4) {
        int s0 = csr_src[k],     s1 = csr_src[k + 1];
        int s2 = csr_src[k + 2], s3 = csr_src[k + 3];
        const float* r0 = xt + (long long)s0 * NM;
        const float* r1 = xt + (long long)s1 * NM;
        const float* r2 = xt + (long long)s2 * NM;
        const float* r3 = xt + (long long)s3 * NM;
        int c0 = cnt[s0], c1 = cnt[s1], c2 = cnt[s2], c3 = cnt[s3];
        float a0 = r0[lane], a1 = r1[lane], a2 = r2[lane], a3 = r3[lane];
        float b0 = 0.f, b1 = 0.f, b2 = 0.f, b3 = 0.f;
        if (lane < 32) {
            b0 = r0[64 + lane]; b1 = r1[64 + lane];
            b2 = r2[64 + lane]; b3 = r3[64 + lane];
        }
        float w0 = dn * rsqrtf((float)(c0 + 1));
        float w1 = dn * rsqrtf((float)(c1 + 1));
        float w2 = dn * rsqrtf((float)(c2 + 1));
        float w3 = dn * rsqrtf((float)(c3 + 1));
        acc0 = fmaf(w0, a0, acc0); acc1 = fmaf(w0, b0, acc1);
        acc0 = fmaf(w1, a1, acc0); acc1 = fmaf(w1, b1, acc1);
        acc0 = fmaf(w2, a2, acc0); acc1 = fmaf(w2, b2, acc1);
        acc0 = fmaf(w3, a3, acc0); acc1 = fmaf(w3, b3, acc1);
    }
    for (; k < end; ++k) {
        int s = csr_src[k];
        const float* rows = xt + (long long)s * NM;
        float ws_ = dn * rsqrtf((float)(cnt[s] + 1));
        acc0 = fmaf(ws_, rows[lane], acc0);
        if (lane < 32) acc1 = fmaf(ws_, rows[64 + lane], acc1);
    }

    sx[w * NM + lane] = acc0;
    if (lane < 32) sx[w * NM + 64 + lane] = acc1;
    __syncthreads();

    // ---- gates: lane handles (b0, j) and (b0+2, j) ----
    const int j = lane & 31, b0_ = lane >> 5;
    const float wz0 = se[j],      wz1 = se[32 + j],  bz = se[64 + j];
    const float wh0 = se[96 + j], wh1 = se[128 + j], bh = se[160 + j];
#pragma unroll
    for (int bi = 0; bi < 2; ++bi) {
        const int b = b0_ + 2 * bi;
        const float* srow = sx + w * NM + b * FT;
        float a = 0.f;
#pragma unroll
        for (int t = 0; t < TT; ++t) {
            float v0 = srow[t], v1 = srow[12 + t], p = se[192 + t];
            float zp = fmaf(v1, wz1, fmaf(v0, wz0, bz));
            float inv = __builtin_amdgcn_rcpf(1.0f + __expf(zp));   // 1 - sigmoid
            float hp = fmaf(v1, wh1, fmaf(v0, wh0, bh));
            hp = fminf(fmaxf(hp + hp, -30.0f), 30.0f);
            float e2 = __expf(hp);
            float h  = (e2 - 1.0f) * __builtin_amdgcn_rcpf(e2 + 1.0f);  // tanh
            a = fmaf(p * inv, h, a);
        }
        lacc[w * 132 + b * 33 + j] = fmaxf(a, 0.f);
    }
    __syncthreads();

    // ---- head: lanes 0..47 produce (b, k) ----
    if (lane < 48) {
        int b = lane / 12, kk = lane - 12 * b;
        float r = shb[kk];
        const float* la = lacc + w * 132 + b * 33;
#pragma unroll
        for (int jj = 0; jj < 32; ++jj)
            r = fmaf(la[jj], shw[jj * 12 + kk], r);
        out[((long long)b * NN + n) * 12 + kk] = r;
    }
}

extern "C" void kernel_launch(void* const* d_in, const int* in_sizes, int n_in,
                              void* d_out, int out_size, void* d_ws, size_t ws_size,
                              hipStream_t stream) {
    const float* x   = (const float*)d_in[0];
    const int*   ei  = (const int*)d_in[1];     // (2,E): [0,E)=src, [E,2E)=dst
    const float* att = (const float*)d_in[2];
    const float* czw = (const float*)d_in[3];
    const float* czb = (const float*)d_in[4];
    const float* lzw = (const float*)d_in[5];
    const float* lzb = (const float*)d_in[6];
    // d_in[7..10] (conv_r / lin_r) dead: H0 == 0 so H0*R == 0
    const float* chw = (const float*)d_in[11];
    const float* chb = (const float*)d_in[12];
    const float* lhw = (const float*)d_in[13];
    const float* lhb = (const float*)d_in[14];
    const float* hw  = (const float*)d_in[15];
    const float* hb  = (const float*)d_in[16];
    float* out = (float*)d_out;

    float* ws = (float*)d_ws;
    int*   cnt  = (int*)(ws + WS_CNT);
    int*   off  = (int*)(ws + WS_OFF);
    int*   btot = (int*)(ws + WS_BT);
    float* eff  = ws + WS_EFF;
    int*   csr  = (int*)(ws + WS_CSR);
    float* xt   = ws + WS_XT;

    const int* src = ei;
    const int* dst = ei + EE;

    k_pre<<<TRB + 1, 256, 0, stream>>>(x, czw, czb, lzw, lzb, chw, chb,
                                       lhw, lhb, att, xt, cnt, eff);
    k_count<<<(EE + 255) / 256, 256, 0, stream>>>(dst, cnt);
    k_scan_local<<<SCAN_BLOCKS, 256, 0, stream>>>(cnt, off, btot);
    k_scan_add<<<SCAN_BLOCKS, 256, 0, stream>>>(off, btot);
    k_fill<<<(EE + 255) / 256, 256, 0, stream>>>(src, dst, off, csr);
    k_fused<<<NN / 4, 256, 0, stream>>>(xt, cnt, off, csr, eff, hw, hb, out);
}

// Round 6
// 152.076 us; speedup vs baseline: 2.7872x; 1.1436x over previous
//
#include <hip/hip_runtime.h>

// Problem constants
#define BB   4
#define NN   30000
#define TT   12
#define EE   240000
#define FT   24        // F_IN * T floats per (b, node)
#define NM   96        // BB * FT: node-major row length
#define CAP  32        // bucket capacity per node (deg is Poisson(8); max ~22)
#define OVCAP 2048     // overflow capacity (normally 0 used)
#define TRB  (NN * NM / 256)         // 11250 transpose blocks
#define FB   ((EE + 255) / 256)      // 938 fill blocks

// Workspace layout (4-byte elements), total 3,874,368 (~15.5 MB):
//   cnt[NN]          @ 0            (zeroed by memset)
//   ovf_cnt[16]      @ 30000        (zeroed by memset; [0] used)
//   eff[256]  float  @ 30016
//   ovf[2*OVCAP] int @ 30272        ((dst,src) pairs)
//   bucket[NN*CAP]   @ 34368
//   xt[NN*96] float  @ 994368       (node-major features)
#define WS_CNT 0
#define WS_OVC 30000
#define WS_EFF 30016
#define WS_OVF 30272
#define WS_BKT 34368
#define WS_XT  994368

// ---- one launch: transpose x -> xt | bucket-fill | weight fold ------------
// eff: Wz0[32] Wz1[32] bz[32] Wh0[32] Wh1[32] bh[32] probs[12]
__global__ void __launch_bounds__(256)
k_pre(const float* __restrict__ x, const int* __restrict__ src,
      const int* __restrict__ dst,
      const float* __restrict__ czw, const float* __restrict__ czb,
      const float* __restrict__ lzw, const float* __restrict__ lzb,
      const float* __restrict__ chw, const float* __restrict__ chb,
      const float* __restrict__ lhw, const float* __restrict__ lhb,
      const float* __restrict__ att,
      float* __restrict__ xt, int* __restrict__ cnt, int* __restrict__ ovc,
      int* __restrict__ ovf, int* __restrict__ bucket, float* __restrict__ eff) {
    int bid = blockIdx.x, lt = threadIdx.x;
    if (bid < TRB) {
        // transpose: xt[n*96 + b*24 + ft] = x[(b*NN + n)*24 + ft]
        int tid = bid * 256 + lt;
        int n = tid / NM, c = tid - NM * n;
        int b = c / FT, ft = c - FT * b;
        xt[tid] = x[(b * NN + n) * FT + ft];
        return;
    }
    if (bid < TRB + FB) {
        // bucket fill: one atomic pass, no scan
        int e = (bid - TRB) * 256 + lt;
        if (e < EE) {
            int d = dst[e], s = src[e];
            int slot = atomicAdd(&cnt[d], 1);
            if (slot < CAP) {
                bucket[d * CAP + slot] = s;
            } else {
                int o = atomicAdd(ovc, 1);
                if (o < OVCAP) { ovf[2 * o] = d; ovf[2 * o + 1] = s; }
            }
        }
        return;
    }
    // last block: weight folding + attention softmax
    int j = lt;
    if (j < 32) {
        float wz0 = 0.f, wz1 = 0.f, bz = 0.f, wh0 = 0.f, wh1 = 0.f, bh = 0.f;
        for (int k = 0; k < 32; ++k) {
            float lz = lzw[k * 32 + j], lh = lhw[k * 32 + j];
            wz0 = fmaf(czw[k],      lz, wz0);
            wz1 = fmaf(czw[32 + k], lz, wz1);
            bz  = fmaf(czb[k],      lz, bz);
            wh0 = fmaf(chw[k],      lh, wh0);
            wh1 = fmaf(chw[32 + k], lh, wh1);
            bh  = fmaf(chb[k],      lh, bh);
        }
        eff[j]        = wz0;
        eff[32 + j]   = wz1;
        eff[64 + j]   = bz + lzb[j];
        eff[96 + j]   = wh0;
        eff[128 + j]  = wh1;
        eff[160 + j]  = bh + lhb[j];
    } else if (j == 32) {
        float m = -1e30f;
        for (int t = 0; t < TT; ++t) m = fmaxf(m, att[t]);
        float p[TT], s = 0.f;
        for (int t = 0; t < TT; ++t) { p[t] = __expf(att[t] - m); s += p[t]; }
        float inv = 1.0f / s;
        for (int t = 0; t < TT; ++t) eff[192 + t] = p[t] * inv;
    }
}

// ---- fused gather + gates + head: one wave per node -----------------------
// agg = dn * ( dn*x_n + sum_s dinv_s * x_s ); rows loaded float2 on 48 lanes.
__global__ void __launch_bounds__(256)
k_fused(const float* __restrict__ xt, const int* __restrict__ cnt,
        const int* __restrict__ ovc, const int* __restrict__ ovf,
        const int* __restrict__ bucket, const float* __restrict__ eff,
        const float* __restrict__ hw, const float* __restrict__ hb,
        float* __restrict__ out) {
    __shared__ float se[204];          // folded weights + probs
    __shared__ float shw[384];         // head_w (32x12)
    __shared__ float shb[12];          // head_b
    __shared__ float sx[4 * NM];       // per-wave aggregated row
    __shared__ float lacc[4 * 132];    // per-wave relu'd hidden (stride 33)
    const int lt = threadIdx.x, lane = lt & 63, w = lt >> 6;
    const int n = blockIdx.x * 4 + w;  // 7500 blocks * 4 waves = 30000 nodes

    if (lt < 204) se[lt] = eff[lt];
    if (lt >= 204 && lt < 216) shb[lt - 204] = hb[lt - 204];
    shw[lt] = hw[lt];
    if (lt < 128) shw[256 + lt] = hw[256 + lt];
    __syncthreads();

    // ---- gather ----
    const int deg = __builtin_amdgcn_readfirstlane(cnt[n]);
    const float dn = rsqrtf((float)(deg + 1));
    const bool act = (lane < 48);

    float2 acc = {0.f, 0.f};
    {
        const float2* rn = (const float2*)(xt + (long long)n * NM);
        if (act) { float2 v = rn[lane]; acc.x = dn * v.x; acc.y = dn * v.y; }
    }

    const int m = (deg < CAP) ? deg : CAP;
    const int* brow = bucket + n * CAP;
    int k = 0;
    for (; k + 4 <= m; k += 4) {
        int s0 = __builtin_amdgcn_readfirstlane(brow[k]);
        int s1 = __builtin_amdgcn_readfirstlane(brow[k + 1]);
        int s2 = __builtin_amdgcn_readfirstlane(brow[k + 2]);
        int s3 = __builtin_amdgcn_readfirstlane(brow[k + 3]);
        int c0 = __builtin_amdgcn_readfirstlane(cnt[s0]);
        int c1 = __builtin_amdgcn_readfirstlane(cnt[s1]);
        int c2 = __builtin_amdgcn_readfirstlane(cnt[s2]);
        int c3 = __builtin_amdgcn_readfirstlane(cnt[s3]);
        const float2* r0 = (const float2*)(xt + (long long)s0 * NM);
        const float2* r1 = (const float2*)(xt + (long long)s1 * NM);
        const float2* r2 = (const float2*)(xt + (long long)s2 * NM);
        const float2* r3 = (const float2*)(xt + (long long)s3 * NM);
        float w0 = rsqrtf((float)(c0 + 1));
        float w1 = rsqrtf((float)(c1 + 1));
        float w2 = rsqrtf((float)(c2 + 1));
        float w3 = rsqrtf((float)(c3 + 1));
        if (act) {
            float2 v0 = r0[lane], v1 = r1[lane], v2 = r2[lane], v3 = r3[lane];
            acc.x = fmaf(w0, v0.x, acc.x); acc.y = fmaf(w0, v0.y, acc.y);
            acc.x = fmaf(w1, v1.x, acc.x); acc.y = fmaf(w1, v1.y, acc.y);
            acc.x = fmaf(w2, v2.x, acc.x); acc.y = fmaf(w2, v2.y, acc.y);
            acc.x = fmaf(w3, v3.x, acc.x); acc.y = fmaf(w3, v3.y, acc.y);
        }
    }
    for (; k < m; ++k) {
        int s = __builtin_amdgcn_readfirstlane(brow[k]);
        int cs = __builtin_amdgcn_readfirstlane(cnt[s]);
        const float2* rs = (const float2*)(xt + (long long)s * NM);
        float ws_ = rsqrtf((float)(cs + 1));
        if (act) {
            float2 v = rs[lane];
            acc.x = fmaf(ws_, v.x, acc.x); acc.y = fmaf(ws_, v.y, acc.y);
        }
    }

    // overflow edges (normally zero)
    int nov = __builtin_amdgcn_readfirstlane(*ovc);
    if (nov > OVCAP) nov = OVCAP;
    for (int i = 0; i < nov; ++i) {
        int d = ovf[2 * i];
        if (d == n) {
            int s = ovf[2 * i + 1];
            int cs = cnt[s];
            float ws_ = rsqrtf((float)(cs + 1));
            const float2* rs = (const float2*)(xt + (long long)s * NM);
            if (act) {
                float2 v = rs[lane];
                acc.x = fmaf(ws_, v.x, acc.x); acc.y = fmaf(ws_, v.y, acc.y);
            }
        }
    }

    if (act) {
        sx[w * NM + 2 * lane]     = dn * acc.x;
        sx[w * NM + 2 * lane + 1] = dn * acc.y;
    }
    __syncthreads();

    // ---- gates: lane handles (b0, j) and (b0+2, j) ----
    const int j = lane & 31, b0_ = lane >> 5;
    const float wz0 = se[j],      wz1 = se[32 + j],  bz = se[64 + j];
    const float wh0 = se[96 + j], wh1 = se[128 + j], bh = se[160 + j];
#pragma unroll
    for (int bi = 0; bi < 2; ++bi) {
        const int b = b0_ + 2 * bi;
        const float* srow = sx + w * NM + b * FT;
        float a = 0.f;
#pragma unroll
        for (int t = 0; t < TT; ++t) {
            float v0 = srow[t], v1 = srow[12 + t], p = se[192 + t];
            float zp = fmaf(v1, wz1, fmaf(v0, wz0, bz));
            float inv = __builtin_amdgcn_rcpf(1.0f + __expf(zp));   // 1 - sigmoid
            float hp = fmaf(v1, wh1, fmaf(v0, wh0, bh));
            hp = fminf(fmaxf(hp + hp, -30.0f), 30.0f);
            float e2 = __expf(hp);
            float h  = (e2 - 1.0f) * __builtin_amdgcn_rcpf(e2 + 1.0f);  // tanh
            a = fmaf(p * inv, h, a);
        }
        lacc[w * 132 + b * 33 + j] = fmaxf(a, 0.f);
    }
    __syncthreads();

    // ---- head: lanes 0..47 produce (b, k) ----
    if (lane < 48) {
        int b = lane / 12, kk = lane - 12 * b;
        float r = shb[kk];
        const float* la = lacc + w * 132 + b * 33;
#pragma unroll
        for (int jj = 0; jj < 32; ++jj)
            r = fmaf(la[jj], shw[jj * 12 + kk], r);
        out[((long long)b * NN + n) * 12 + kk] = r;
    }
}

extern "C" void kernel_launch(void* const* d_in, const int* in_sizes, int n_in,
                              void* d_out, int out_size, void* d_ws, size_t ws_size,
                              hipStream_t stream) {
    const float* x   = (const float*)d_in[0];
    const int*   ei  = (const int*)d_in[1];     // (2,E): [0,E)=src, [E,2E)=dst
    const float* att = (const float*)d_in[2];
    const float* czw = (const float*)d_in[3];
    const float* czb = (const float*)d_in[4];
    const float* lzw = (const float*)d_in[5];
    const float* lzb = (const float*)d_in[6];
    // d_in[7..10] (conv_r / lin_r) dead: H0 == 0 so H0*R == 0
    const float* chw = (const float*)d_in[11];
    const float* chb = (const float*)d_in[12];
    const float* lhw = (const float*)d_in[13];
    const float* lhb = (const float*)d_in[14];
    const float* hw  = (const float*)d_in[15];
    const float* hb  = (const float*)d_in[16];
    float* out = (float*)d_out;

    float* ws = (float*)d_ws;
    int*   cnt = (int*)(ws + WS_CNT);
    int*   ovc = (int*)(ws + WS_OVC);
    float* eff = ws + WS_EFF;
    int*   ovf = (int*)(ws + WS_OVF);
    int*   bkt = (int*)(ws + WS_BKT);
    float* xt  = ws + WS_XT;

    const int* src = ei;
    const int* dst = ei + EE;

    hipMemsetAsync(cnt, 0, (WS_EFF) * 4, stream);   // zero cnt + ovf_cnt
    k_pre<<<TRB + FB + 1, 256, 0, stream>>>(x, src, dst, czw, czb, lzw, lzb,
                                            chw, chb, lhw, lhb, att,
                                            xt, cnt, ovc, ovf, bkt, eff);
    k_fused<<<NN / 4, 256, 0, stream>>>(xt, cnt, ovc, ovf, bkt, eff, hw, hb, out);
}

// Round 7
// 145.977 us; speedup vs baseline: 2.9036x; 1.0418x over previous
//
#include <hip/hip_runtime.h>

// Problem constants
#define BB   4
#define NN   30000
#define TT   12
#define EE   240000
#define FT   24        // F_IN * T floats per (b, node)
#define NM   96        // BB * FT
#define CAP  32        // bucket capacity per node (deg ~ Poisson(8); max ~22)
#define OVCAP 2048     // overflow capacity (normally 0 used)
#define FB   ((EE + 255) / 256)      // 938 fill blocks

// Workspace layout (4-byte elements), total ~4 MB:
//   cnt[NN]          @ 0            (zeroed by memset)
//   ovf_cnt[16]      @ 30000        (zeroed by memset; [0] used)
//   eff[256]  float  @ 30016
//   ovf[2*OVCAP] int @ 30272        ((dst,src) pairs)
//   bucket[NN*CAP]   @ 34368
#define WS_CNT 0
#define WS_OVC 30000
#define WS_EFF 30016
#define WS_OVF 30272
#define WS_BKT 34368

__device__ __forceinline__ float readlane_f(float v, int l) {
    return __int_as_float(__builtin_amdgcn_readlane(__float_as_int(v), l));
}

// ---- one launch: bucket-fill | weight fold --------------------------------
// eff: Wz0[32] Wz1[32] bz[32] Wh0[32] Wh1[32] bh[32] probs[12]
__global__ void __launch_bounds__(256)
k_pre(const int* __restrict__ src, const int* __restrict__ dst,
      const float* __restrict__ czw, const float* __restrict__ czb,
      const float* __restrict__ lzw, const float* __restrict__ lzb,
      const float* __restrict__ chw, const float* __restrict__ chb,
      const float* __restrict__ lhw, const float* __restrict__ lhb,
      const float* __restrict__ att,
      int* __restrict__ cnt, int* __restrict__ ovc,
      int* __restrict__ ovf, int* __restrict__ bucket, float* __restrict__ eff) {
    int bid = blockIdx.x, lt = threadIdx.x;
    if (bid < FB) {
        // bucket fill: one atomic pass, no scan
        int e = bid * 256 + lt;
        if (e < EE) {
            int d = dst[e], s = src[e];
            int slot = atomicAdd(&cnt[d], 1);
            if (slot < CAP) {
                bucket[d * CAP + slot] = s;
            } else {
                int o = atomicAdd(ovc, 1);
                if (o < OVCAP) { ovf[2 * o] = d; ovf[2 * o + 1] = s; }
            }
        }
        return;
    }
    // last block: weight folding + attention softmax
    int j = lt;
    if (j < 32) {
        float wz0 = 0.f, wz1 = 0.f, bz = 0.f, wh0 = 0.f, wh1 = 0.f, bh = 0.f;
        for (int k = 0; k < 32; ++k) {
            float lz = lzw[k * 32 + j], lh = lhw[k * 32 + j];
            wz0 = fmaf(czw[k],      lz, wz0);
            wz1 = fmaf(czw[32 + k], lz, wz1);
            bz  = fmaf(czb[k],      lz, bz);
            wh0 = fmaf(chw[k],      lh, wh0);
            wh1 = fmaf(chw[32 + k], lh, wh1);
            bh  = fmaf(chb[k],      lh, bh);
        }
        eff[j]        = wz0;
        eff[32 + j]   = wz1;
        eff[64 + j]   = bz + lzb[j];
        eff[96 + j]   = wh0;
        eff[128 + j]  = wh1;
        eff[160 + j]  = bh + lhb[j];
    } else if (j == 32) {
        float m = -1e30f;
        for (int t = 0; t < TT; ++t) m = fmaxf(m, att[t]);
        float p[TT], s = 0.f;
        for (int t = 0; t < TT; ++t) { p[t] = __expf(att[t] - m); s += p[t]; }
        float inv = 1.0f / s;
        for (int t = 0; t < TT; ++t) eff[192 + t] = p[t] * inv;
    }
}

// ---- fused gather + gates + head: one wave per node -----------------------
// Reads x in native (B,N,24) layout: lane<48 -> (b=lane/12, f2=lane%12),
// one dwordx2 per edge. Source list + per-edge weights fetched ONCE per wave
// into lanes, then broadcast via v_readlane (no per-edge memory chain).
__global__ void __launch_bounds__(256)
k_fused(const float* __restrict__ x, const int* __restrict__ cnt,
        const int* __restrict__ ovc, const int* __restrict__ ovf,
        const int* __restrict__ bucket, const float* __restrict__ eff,
        const float* __restrict__ hw, const float* __restrict__ hb,
        float* __restrict__ out) {
    __shared__ float se[204];          // folded weights + probs
    __shared__ float shw[384];         // head_w (32x12)
    __shared__ float shb[12];          // head_b
    __shared__ float sx[4 * NM];       // per-wave aggregated row
    __shared__ float lacc[4 * 132];    // per-wave relu'd hidden (stride 33)
    const int lt = threadIdx.x, lane = lt & 63, w = lt >> 6;
    const int n = blockIdx.x * 4 + w;  // 7500 blocks * 4 waves = 30000 nodes

    if (lt < 204) se[lt] = eff[lt];
    if (lt >= 204 && lt < 216) shb[lt - 204] = hb[lt - 204];
    shw[lt] = hw[lt];
    if (lt < 128) shw[256 + lt] = hw[256 + lt];
    __syncthreads();

    const bool act = (lane < 48);
    const int b = lane / 12, f2 = lane - 12 * b;       // valid when lane<48
    const float2* xb = (const float2*)x;
    const int lane_off = b * (NN * 12) + f2;           // float2 units

    // ---- per-wave edge list: sv[lane] = source, wv[lane] = rsqrt(deg_s+1)
    // lane m = self loop (sv=n, wv=dn); lanes (m, mm4) padded with wv=0.
    const int deg = __builtin_amdgcn_readfirstlane(cnt[n]);
    const int m = (deg < CAP) ? deg : CAP;
    int sv = (lane < m) ? bucket[n * CAP + lane] : n;
    float wv = (lane <= m) ? rsqrtf((float)(cnt[sv] + 1)) : 0.f;

    float2 acc = {0.f, 0.f};
    const int mm4 = (m + 4) & ~3;      // (m+1) rounded up to multiple of 4
    for (int k = 0; k < mm4; k += 4) {
        int s0 = __builtin_amdgcn_readlane(sv, k);
        int s1 = __builtin_amdgcn_readlane(sv, k + 1);
        int s2 = __builtin_amdgcn_readlane(sv, k + 2);
        int s3 = __builtin_amdgcn_readlane(sv, k + 3);
        float w0 = readlane_f(wv, k);
        float w1 = readlane_f(wv, k + 1);
        float w2 = readlane_f(wv, k + 2);
        float w3 = readlane_f(wv, k + 3);
        if (act) {
            float2 v0 = xb[lane_off + s0 * 12];
            float2 v1 = xb[lane_off + s1 * 12];
            float2 v2 = xb[lane_off + s2 * 12];
            float2 v3 = xb[lane_off + s3 * 12];
            acc.x = fmaf(w0, v0.x, acc.x); acc.y = fmaf(w0, v0.y, acc.y);
            acc.x = fmaf(w1, v1.x, acc.x); acc.y = fmaf(w1, v1.y, acc.y);
            acc.x = fmaf(w2, v2.x, acc.x); acc.y = fmaf(w2, v2.y, acc.y);
            acc.x = fmaf(w3, v3.x, acc.x); acc.y = fmaf(w3, v3.y, acc.y);
        }
    }

    // overflow edges (normally zero)
    int nov = __builtin_amdgcn_readfirstlane(*ovc);
    if (nov > 0) {
        if (nov > OVCAP) nov = OVCAP;
        for (int i = 0; i < nov; ++i) {
            int d = ovf[2 * i];
            if (d == n) {
                int s = ovf[2 * i + 1];
                float ws_ = rsqrtf((float)(cnt[s] + 1));
                if (act) {
                    float2 v = xb[lane_off + s * 12];
                    acc.x = fmaf(ws_, v.x, acc.x);
                    acc.y = fmaf(ws_, v.y, acc.y);
                }
            }
        }
    }

    const float dn = readlane_f(wv, m);   // rsqrt(deg_n + 1)
    if (act) {
        sx[w * NM + b * FT + f2 * 2]     = dn * acc.x;
        sx[w * NM + b * FT + f2 * 2 + 1] = dn * acc.y;
    }
    __syncthreads();

    // ---- gates: lane handles (b0, j) and (b0+2, j) ----
    const int j = lane & 31, b0_ = lane >> 5;
    const float wz0 = se[j],      wz1 = se[32 + j],  bz = se[64 + j];
    const float wh0 = se[96 + j], wh1 = se[128 + j], bh = se[160 + j];
#pragma unroll
    for (int bi = 0; bi < 2; ++bi) {
        const int bb = b0_ + 2 * bi;
        const float* srow = sx + w * NM + bb * FT;
        float a = 0.f;
#pragma unroll
        for (int t = 0; t < TT; ++t) {
            float v0 = srow[t], v1 = srow[12 + t], p = se[192 + t];
            float zp = fmaf(v1, wz1, fmaf(v0, wz0, bz));
            float inv = __builtin_amdgcn_rcpf(1.0f + __expf(zp));   // 1 - sigmoid
            float hp = fmaf(v1, wh1, fmaf(v0, wh0, bh));
            hp = fminf(fmaxf(hp + hp, -30.0f), 30.0f);
            float e2 = __expf(hp);
            float h  = (e2 - 1.0f) * __builtin_amdgcn_rcpf(e2 + 1.0f);  // tanh
            a = fmaf(p * inv, h, a);
        }
        lacc[w * 132 + bb * 33 + j] = fmaxf(a, 0.f);
    }
    __syncthreads();

    // ---- head: lanes 0..47 produce (b, k) ----
    if (lane < 48) {
        int bb = lane / 12, kk = lane - 12 * bb;
        float r = shb[kk];
        const float* la = lacc + w * 132 + bb * 33;
#pragma unroll
        for (int jj = 0; jj < 32; ++jj)
            r = fmaf(la[jj], shw[jj * 12 + kk], r);
        out[((long long)bb * NN + n) * 12 + kk] = r;
    }
}

extern "C" void kernel_launch(void* const* d_in, const int* in_sizes, int n_in,
                              void* d_out, int out_size, void* d_ws, size_t ws_size,
                              hipStream_t stream) {
    const float* x   = (const float*)d_in[0];
    const int*   ei  = (const int*)d_in[1];     // (2,E): [0,E)=src, [E,2E)=dst
    const float* att = (const float*)d_in[2];
    const float* czw = (const float*)d_in[3];
    const float* czb = (const float*)d_in[4];
    const float* lzw = (const float*)d_in[5];
    const float* lzb = (const float*)d_in[6];
    // d_in[7..10] (conv_r / lin_r) dead: H0 == 0 so H0*R == 0
    const float* chw = (const float*)d_in[11];
    const float* chb = (const float*)d_in[12];
    const float* lhw = (const float*)d_in[13];
    const float* lhb = (const float*)d_in[14];
    const float* hw  = (const float*)d_in[15];
    const float* hb  = (const float*)d_in[16];
    float* out = (float*)d_out;

    float* ws = (float*)d_ws;
    int*   cnt = (int*)(ws + WS_CNT);
    int*   ovc = (int*)(ws + WS_OVC);
    float* eff = ws + WS_EFF;
    int*   ovf = (int*)(ws + WS_OVF);
    int*   bkt = (int*)(ws + WS_BKT);

    const int* src = ei;
    const int* dst = ei + EE;

    hipMemsetAsync(cnt, 0, WS_EFF * 4, stream);   // zero cnt + ovf_cnt
    k_pre<<<FB + 1, 256, 0, stream>>>(src, dst, czw, czb, lzw, lzb,
                                      chw, chb, lhw, lhb, att,
                                      cnt, ovc, ovf, bkt, eff);
    k_fused<<<NN / 4, 256, 0, stream>>>(x, cnt, ovc, ovf, bkt, eff, hw, hb, out);
}

// Round 8
// 141.812 us; speedup vs baseline: 2.9889x; 1.0294x over previous
//
#include <hip/hip_runtime.h>

// Problem constants
#define BB   4
#define NN   30000
#define TT   12
#define EE   240000
#define FT   24        // F_IN * T floats per (b, node)
#define NM   96        // BB * FT
#define CAP  32        // bucket capacity per node (deg ~ Poisson(8); max ~22)
#define OVCAP 2048     // overflow capacity (normally 0 used)
#define FB   ((EE + 255) / 256)      // 938 fill blocks
#define LOG2E 1.44269504088896340736f

// Workspace layout (4-byte elements), total ~4 MB:
//   cnt[NN]          @ 0            (zeroed by memset)
//   ovf_cnt[16]      @ 30000        (zeroed by memset; [0] used)
//   eff[256]  float  @ 30016
//   ovf[2*OVCAP] int @ 30272        ((dst,src) pairs)
//   bucket[NN*CAP]   @ 34368
#define WS_CNT 0
#define WS_OVC 30000
#define WS_EFF 30016
#define WS_OVF 30272
#define WS_BKT 34368

__device__ __forceinline__ float readlane_f(float v, int l) {
    return __int_as_float(__builtin_amdgcn_readlane(__float_as_int(v), l));
}

// ---- one launch: bucket-fill | weight fold --------------------------------
// eff layout: Az0[32] Az1[32] ab[32] Ch0[32] Ch1[32] cb[32] probs[12]
// where A* = -log2e * (Wz folded), C* = 2*log2e * (Wh folded):
//   a = Az0*v0 + Az1*v1 + ab  -> u  = exp2(a) = exp(-zp)
//   c = Ch0*v0 + Ch1*v1 + cb  -> e2 = exp2(c) = exp(2*hp)
__global__ void __launch_bounds__(256)
k_pre(const int* __restrict__ src, const int* __restrict__ dst,
      const float* __restrict__ czw, const float* __restrict__ czb,
      const float* __restrict__ lzw, const float* __restrict__ lzb,
      const float* __restrict__ chw, const float* __restrict__ chb,
      const float* __restrict__ lhw, const float* __restrict__ lhb,
      const float* __restrict__ att,
      int* __restrict__ cnt, int* __restrict__ ovc,
      int* __restrict__ ovf, int* __restrict__ bucket, float* __restrict__ eff) {
    int bid = blockIdx.x, lt = threadIdx.x;
    if (bid < FB) {
        int e = bid * 256 + lt;
        if (e < EE) {
            int d = dst[e], s = src[e];
            int slot = atomicAdd(&cnt[d], 1);
            if (slot < CAP) {
                bucket[d * CAP + slot] = s;
            } else {
                int o = atomicAdd(ovc, 1);
                if (o < OVCAP) { ovf[2 * o] = d; ovf[2 * o + 1] = s; }
            }
        }
        return;
    }
    // last block: weight folding + attention softmax
    int j = lt;
    if (j < 32) {
        float wz0 = 0.f, wz1 = 0.f, bz = 0.f, wh0 = 0.f, wh1 = 0.f, bh = 0.f;
        for (int k = 0; k < 32; ++k) {
            float lz = lzw[k * 32 + j], lh = lhw[k * 32 + j];
            wz0 = fmaf(czw[k],      lz, wz0);
            wz1 = fmaf(czw[32 + k], lz, wz1);
            bz  = fmaf(czb[k],      lz, bz);
            wh0 = fmaf(chw[k],      lh, wh0);
            wh1 = fmaf(chw[32 + k], lh, wh1);
            bh  = fmaf(chb[k],      lh, bh);
        }
        eff[j]        = -LOG2E * wz0;
        eff[32 + j]   = -LOG2E * wz1;
        eff[64 + j]   = -LOG2E * (bz + lzb[j]);
        eff[96 + j]   = 2.0f * LOG2E * wh0;
        eff[128 + j]  = 2.0f * LOG2E * wh1;
        eff[160 + j]  = 2.0f * LOG2E * (bh + lhb[j]);
    } else if (j == 32) {
        float m = -1e30f;
        for (int t = 0; t < TT; ++t) m = fmaxf(m, att[t]);
        float p[TT], s = 0.f;
        for (int t = 0; t < TT; ++t) { p[t] = __expf(att[t] - m); s += p[t]; }
        float inv = 1.0f / s;
        for (int t = 0; t < TT; ++t) eff[192 + t] = p[t] * inv;
    }
}

// ---- fused gather + gates + head: one wave per node -----------------------
__global__ void __launch_bounds__(256)
k_fused(const float* __restrict__ x, const int* __restrict__ cnt,
        const int* __restrict__ ovc, const int* __restrict__ ovf,
        const int* __restrict__ bucket, const float* __restrict__ eff,
        const float* __restrict__ hw, const float* __restrict__ hb,
        float* __restrict__ out) {
    __shared__ float se[204];          // folded weights + probs
    __shared__ float shw[384];         // head_w (32x12)
    __shared__ float shb[12];          // head_b
    __shared__ float sx[4 * NM];       // per-wave aggregated row
    __shared__ float lacc[4 * 132];    // per-wave relu'd hidden (stride 33)
    const int lt = threadIdx.x, lane = lt & 63, w = lt >> 6;
    const int n = blockIdx.x * 4 + w;  // 7500 blocks * 4 waves = 30000 nodes

    if (lt < 204) se[lt] = eff[lt];
    if (lt >= 204 && lt < 216) shb[lt - 204] = hb[lt - 204];
    shw[lt] = hw[lt];
    if (lt < 128) shw[256 + lt] = hw[256 + lt];
    __syncthreads();

    const bool act = (lane < 48);
    const int b = lane / 12, f2 = lane - 12 * b;       // valid when lane<48
    const float2* xb = (const float2*)x;
    const int lane_off = b * (NN * 12) + f2;           // float2 units

    // per-wave edge list: sv[lane] = source, wv[lane] = rsqrt(deg_s+1)
    // lane m = self loop (sv=n, wv=dn); lanes (m, mm8) padded with wv=0.
    const int deg = __builtin_amdgcn_readfirstlane(cnt[n]);
    const int m = (deg < CAP) ? deg : CAP;
    int sv = (lane < m) ? bucket[n * CAP + lane] : n;
    float wv = (lane <= m) ? rsqrtf((float)(cnt[sv] + 1)) : 0.f;

    float2 acc = {0.f, 0.f};
    const int mm8 = (m + 8) & ~7;      // (m+1) rounded up to multiple of 8
    for (int k = 0; k < mm8; k += 8) {
        int s0 = __builtin_amdgcn_readlane(sv, k);
        int s1 = __builtin_amdgcn_readlane(sv, k + 1);
        int s2 = __builtin_amdgcn_readlane(sv, k + 2);
        int s3 = __builtin_amdgcn_readlane(sv, k + 3);
        int s4 = __builtin_amdgcn_readlane(sv, k + 4);
        int s5 = __builtin_amdgcn_readlane(sv, k + 5);
        int s6 = __builtin_amdgcn_readlane(sv, k + 6);
        int s7 = __builtin_amdgcn_readlane(sv, k + 7);
        if (act) {
            // all 8 loads independent -> issued back-to-back (1 round-trip)
            float2 v0 = xb[lane_off + s0 * 12];
            float2 v1 = xb[lane_off + s1 * 12];
            float2 v2 = xb[lane_off + s2 * 12];
            float2 v3 = xb[lane_off + s3 * 12];
            float2 v4 = xb[lane_off + s4 * 12];
            float2 v5 = xb[lane_off + s5 * 12];
            float2 v6 = xb[lane_off + s6 * 12];
            float2 v7 = xb[lane_off + s7 * 12];
            float w0 = readlane_f(wv, k),     w1 = readlane_f(wv, k + 1);
            float w2 = readlane_f(wv, k + 2), w3 = readlane_f(wv, k + 3);
            float w4 = readlane_f(wv, k + 4), w5 = readlane_f(wv, k + 5);
            float w6 = readlane_f(wv, k + 6), w7 = readlane_f(wv, k + 7);
            acc.x = fmaf(w0, v0.x, acc.x); acc.y = fmaf(w0, v0.y, acc.y);
            acc.x = fmaf(w1, v1.x, acc.x); acc.y = fmaf(w1, v1.y, acc.y);
            acc.x = fmaf(w2, v2.x, acc.x); acc.y = fmaf(w2, v2.y, acc.y);
            acc.x = fmaf(w3, v3.x, acc.x); acc.y = fmaf(w3, v3.y, acc.y);
            acc.x = fmaf(w4, v4.x, acc.x); acc.y = fmaf(w4, v4.y, acc.y);
            acc.x = fmaf(w5, v5.x, acc.x); acc.y = fmaf(w5, v5.y, acc.y);
            acc.x = fmaf(w6, v6.x, acc.x); acc.y = fmaf(w6, v6.y, acc.y);
            acc.x = fmaf(w7, v7.x, acc.x); acc.y = fmaf(w7, v7.y, acc.y);
        }
    }

    // overflow edges (normally zero)
    int nov = __builtin_amdgcn_readfirstlane(*ovc);
    if (nov > 0) {
        if (nov > OVCAP) nov = OVCAP;
        for (int i = 0; i < nov; ++i) {
            int d = ovf[2 * i];
            if (d == n) {
                int s = ovf[2 * i + 1];
                float ws_ = rsqrtf((float)(cnt[s] + 1));
                if (act) {
                    float2 v = xb[lane_off + s * 12];
                    acc.x = fmaf(ws_, v.x, acc.x);
                    acc.y = fmaf(ws_, v.y, acc.y);
                }
            }
        }
    }

    const float dn = readlane_f(wv, m);   // rsqrt(deg_n + 1)
    if (act) {
        float2* sx2 = (float2*)(sx + w * NM + b * FT);
        sx2[f2] = make_float2(dn * acc.x, dn * acc.y);
    }
    __syncthreads();

    // ---- gates: lane handles (b0, j) and (b0+2, j); merged single-rcp ----
    const int j = lane & 31, b0_ = lane >> 5;
    const float az0 = se[j],      az1 = se[32 + j],  ab = se[64 + j];
    const float ch0 = se[96 + j], ch1 = se[128 + j], cb = se[160 + j];
#pragma unroll
    for (int bi = 0; bi < 2; ++bi) {
        const int bb = b0_ + 2 * bi;
        const float* srow = sx + w * NM + bb * FT;
        float a = 0.f;
#pragma unroll
        for (int t = 0; t < TT; ++t) {
            float v0 = srow[t], v1 = srow[12 + t], p = se[192 + t];
            float ae = fmaf(v1, az1, fmaf(v0, az0, ab));     // -zp*log2e
            float ce = fmaf(v1, ch1, fmaf(v0, ch0, cb));     // 2*hp*log2e
            ae = fminf(fmaxf(ae, -60.f), 60.f);
            ce = fminf(fmaxf(ce, -60.f), 60.f);
            float u  = __builtin_amdgcn_exp2f(ae);           // exp(-zp)
            float e2 = __builtin_amdgcn_exp2f(ce);           // exp(2*hp)
            float t1  = 1.0f + u;
            float den = fmaf(e2, t1, t1);                    // (1+u)(1+e2)
            float num = fmaf(u, e2, -u);                     // u(e2-1)
            float r   = __builtin_amdgcn_rcpf(den);
            a = fmaf(p * num, r, a);                         // += p*(1-z)*tanh
        }
        lacc[w * 132 + bb * 33 + j] = fmaxf(a, 0.f);
    }
    __syncthreads();

    // ---- head: lanes 0..47 produce (b, k) ----
    if (lane < 48) {
        int bb = lane / 12, kk = lane - 12 * bb;
        float r = shb[kk];
        const float* la = lacc + w * 132 + bb * 33;
#pragma unroll
        for (int jj = 0; jj < 32; ++jj)
            r = fmaf(la[jj], shw[jj * 12 + kk], r);
        out[((long long)bb * NN + n) * 12 + kk] = r;
    }
}

extern "C" void kernel_launch(void* const* d_in, const int* in_sizes, int n_in,
                              void* d_out, int out_size, void* d_ws, size_t ws_size,
                              hipStream_t stream) {
    const float* x   = (const float*)d_in[0];
    const int*   ei  = (const int*)d_in[1];     // (2,E): [0,E)=src, [E,2E)=dst
    const float* att = (const float*)d_in[2];
    const float* czw = (const float*)d_in[3];
    const float* czb = (const float*)d_in[4];
    const float* lzw = (const float*)d_in[5];
    const float* lzb = (const float*)d_in[6];
    // d_in[7..10] (conv_r / lin_r) dead: H0 == 0 so H0*R == 0
    const float* chw = (const float*)d_in[11];
    const float* chb = (const float*)d_in[12];
    const float* lhw = (const float*)d_in[13];
    const float* lhb = (const float*)d_in[14];
    const float* hw  = (const float*)d_in[15];
    const float* hb  = (const float*)d_in[16];
    float* out = (float*)d_out;

    float* ws = (float*)d_ws;
    int*   cnt = (int*)(ws + WS_CNT);
    int*   ovc = (int*)(ws + WS_OVC);
    float* eff = ws + WS_EFF;
    int*   ovf = (int*)(ws + WS_OVF);
    int*   bkt = (int*)(ws + WS_BKT);

    const int* src = ei;
    const int* dst = ei + EE;

    hipMemsetAsync(cnt, 0, WS_EFF * 4, stream);   // zero cnt + ovf_cnt
    k_pre<<<FB + 1, 256, 0, stream>>>(src, dst, czw, czb, lzw, lzb,
                                      chw, chb, lhw, lhb, att,
                                      cnt, ovc, ovf, bkt, eff);
    k_fused<<<NN / 4, 256, 0, stream>>>(x, cnt, ovc, ovf, bkt, eff, hw, hb, out);
}